// Round 8
// baseline (713.411 us; speedup 1.0000x reference)
//
#include <hip/hip_runtime.h>

#define TT 512   // max sequence length T
#define NN 128   // number of tags N
#define NTHR 256 // 4 waves, 1 per SIMD
#define BD  64   // backtrack chunk depth
#define MAXG 8   // max chunks = ceil((TT-1)/BD)
#define SROW 160 // swizzled state row: 8 chunks x 20 floats (16 used + 4 pad)
#define SW(i) (20 * ((i) >> 4) + ((i) & 15))

// Barrier WITHOUT vmcnt drain: LDS writes drained, global prefetches stay
// in flight (compiler inserts vmcnt waits at use).
#define STEP_BARRIER() asm volatile("s_waitcnt lgkmcnt(0)\n\ts_barrier" ::: "memory")

// DPP cross-lane (pure VALU, no LDS pipe)
template <int CTRL>
__device__ __forceinline__ int dpp_i(int x) {
    return __builtin_amdgcn_update_dpp(x, x, CTRL, 0xf, 0xf, true);
}
template <int CTRL>
__device__ __forceinline__ float dpp_f(float x) {
    union { float f; int i; } u; u.f = x;
    u.i = dpp_i<CTRL>(u.i);
    return u.f;
}
#define DPP_XOR1 0xB1   // quad_perm [1,0,3,2] : lane ^= 1
#define DPP_XOR2 0x4E   // quad_perm [2,3,0,1] : lane ^= 2
#define DPP_MIR7 0x141  // row_half_mirror (lane^=7): == ^4 after stages 1,2

// One block per batch element (256 blocks <-> 256 CUs), 256 threads.
// thread -> (j, c): j = tid>>3 in 0..31, serves tags j+32d (d=0..3);
// c = tid&7 owns i-range [16c, 16c+16). trans in VGPRs (64/thread).
// State double-buffered in LDS, stride-20 chunk swizzle (8 distinct
// bank-quads per b128 slot -> conflict-free). D=4 halves LDS traffic vs
// R5 (16 b128/step/CU). 8 independent scan chains/thread. All-DPP octet
// merge. lgkm-only barrier. Parallel chunked backtrack.
__global__ __launch_bounds__(NTHR, 1)
void crf_viterbi_kernel(const float* __restrict__ logits,
                        const float* __restrict__ trans,
                        const int* __restrict__ seqlen,
                        int* __restrict__ out) {
    __shared__ float stateBuf[2][SROW];
    __shared__ float redV[NN];
    __shared__ int   redI[NN];
    __shared__ int   tagBuf[TT];
    __shared__ int   entryTag[MAXG];
    __shared__ unsigned char bp[TT][NN];          // 64 KiB backpointers
    __shared__ unsigned char hist[MAXG][BD][NN];  // 64 KiB backtrack histories

    const int tid = threadIdx.x;
    const int j   = tid >> 3;   // 0..31; serves tags j, j+32, j+64, j+96
    const int c   = tid & 7;    // i-chunk
    const int i0  = c << 4;
    const int b   = blockIdx.x;
    const int L   = seqlen[b];  // in [1, TT]
    const int jx  = j + ((c & 3) << 5);  // tag whose x this lane loads (c<4 write)

    // Transition chunks: trd[k] = trans[i0+k][j + 32d]   (64 VGPRs)
    float tr0[16], tr1[16], tr2[16], tr3[16];
    #pragma unroll
    for (int k = 0; k < 16; ++k) {
        const float* tp = trans + (i0 + k) * NN + j;
        tr0[k] = tp[0];
        tr1[k] = tp[32];
        tr2[k] = tp[64];
        tr3[k] = tp[96];
    }

    const float* lrow = logits + (size_t)b * TT * NN;

    // t = 0 init (swizzled layout); writer lanes c<4 cover all 128 tags
    if (c < 4) stateBuf[0][SW(jx)] = lrow[jx];
    __syncthreads();

    // x for the current step (consumed by writer lanes c<4)
    float xa = lrow[NN + jx];

    // One Viterbi step: read src, write dst, consume xa, prefetch next x.
    auto vstep = [&](const float* st, float* dst, int t) {
        int tn = t + 1; tn = (tn < TT) ? tn : (TT - 1);
        float xnext = lrow[tn * NN + jx];

        const float* sp = st + 20 * c;
        float4 a0 = *(const float4*)(sp);
        float4 a1 = *(const float4*)(sp + 4);
        float4 a2 = *(const float4*)(sp + 8);
        float4 a3 = *(const float4*)(sp + 12);

        // 4 tags x 2 sub-chains (k 0..7 / 8..15): 8 independent chains.
        // strict > over ascending k == first-occurrence.
        float bA0 = -__builtin_inff(), bA1 = bA0, bA2 = bA0, bA3 = bA0;
        float bB0 = bA0, bB1 = bA0, bB2 = bA0, bB3 = bA0;
        int aA0 = 0, aA1 = 0, aA2 = 0, aA3 = 0;
        int aB0 = 8, aB1 = 8, aB2 = 8, aB3 = 8;
        #define ELEM(S, K, BV0, AR0, BV1, AR1, BV2, AR2, BV3, AR3)              \
        {                                                                       \
            float s0 = (S) + tr0[K];                                            \
            bool g0 = s0 > BV0; BV0 = g0 ? s0 : BV0; AR0 = g0 ? (K) : AR0;      \
            float s1 = (S) + tr1[K];                                            \
            bool g1 = s1 > BV1; BV1 = g1 ? s1 : BV1; AR1 = g1 ? (K) : AR1;      \
            float s2 = (S) + tr2[K];                                            \
            bool g2 = s2 > BV2; BV2 = g2 ? s2 : BV2; AR2 = g2 ? (K) : AR2;      \
            float s3 = (S) + tr3[K];                                            \
            bool g3 = s3 > BV3; BV3 = g3 ? s3 : BV3; AR3 = g3 ? (K) : AR3;      \
        }
        #define ELA(S, K) ELEM(S, K, bA0, aA0, bA1, aA1, bA2, aA2, bA3, aA3)
        #define ELB(S, K) ELEM(S, K, bB0, aB0, bB1, aB1, bB2, aB2, bB3, aB3)
        ELA(a0.x, 0)  ELA(a0.y, 1)  ELA(a0.z, 2)  ELA(a0.w, 3)
        ELA(a1.x, 4)  ELA(a1.y, 5)  ELA(a1.z, 6)  ELA(a1.w, 7)
        ELB(a2.x, 8)  ELB(a2.y, 9)  ELB(a2.z, 10) ELB(a2.w, 11)
        ELB(a3.x, 12) ELB(a3.y, 13) ELB(a3.z, 14) ELB(a3.w, 15)
        #undef ELA
        #undef ELB
        #undef ELEM
        // Combine sub-chains (A indices < B: take B only if strictly >).
        bool gc0 = bB0 > bA0, gc1 = bB1 > bA1, gc2 = bB2 > bA2, gc3 = bB3 > bA3;
        float bv0 = gc0 ? bB0 : bA0, bv1 = gc1 ? bB1 : bA1;
        float bv2 = gc2 ? bB2 : bA2, bv3 = gc3 ? bB3 : bA3;
        int bi0 = i0 + (gc0 ? aB0 : aA0), bi1 = i0 + (gc1 ? aB1 : aA1);
        int bi2 = i0 + (gc2 ? aB2 : aA2), bi3 = i0 + (gc3 ? aB3 : aA3);

        // 3-stage all-DPP merge across the 8 lanes of this tag group.
        // Tie -> lower chunk wins (exact first-occurrence).
        #define MERGE_STAGE(CTRL, LOWER)                                    \
        {                                                                   \
            bool lower = (LOWER);                                           \
            float p0 = dpp_f<CTRL>(bv0); int q0 = dpp_i<CTRL>(bi0);         \
            float p1 = dpp_f<CTRL>(bv1); int q1 = dpp_i<CTRL>(bi1);         \
            float p2 = dpp_f<CTRL>(bv2); int q2 = dpp_i<CTRL>(bi2);         \
            float p3 = dpp_f<CTRL>(bv3); int q3 = dpp_i<CTRL>(bi3);         \
            bool t0 = (p0 > bv0) || (p0 == bv0 && lower);                   \
            bool t1 = (p1 > bv1) || (p1 == bv1 && lower);                   \
            bool t2 = (p2 > bv2) || (p2 == bv2 && lower);                   \
            bool t3 = (p3 > bv3) || (p3 == bv3 && lower);                   \
            bv0 = t0 ? p0 : bv0; bi0 = t0 ? q0 : bi0;                       \
            bv1 = t1 ? p1 : bv1; bi1 = t1 ? q1 : bi1;                       \
            bv2 = t2 ? p2 : bv2; bi2 = t2 ? q2 : bi2;                       \
            bv3 = t3 ? p3 : bv3; bi3 = t3 ? q3 : bi3;                       \
        }
        MERGE_STAGE(DPP_XOR1, (c & 1) != 0)
        MERGE_STAGE(DPP_XOR2, (c & 2) != 0)
        MERGE_STAGE(DPP_MIR7, (c & 4) != 0)
        #undef MERGE_STAGE

        if (c < 4) {   // lane c writes tag j + 32c
            float bv = (c == 0) ? bv0 : (c == 1) ? bv1 : (c == 2) ? bv2 : bv3;
            int   bi = (c == 0) ? bi0 : (c == 1) ? bi1 : (c == 2) ? bi2 : bi3;
            dst[SW(jx)] = bv + xa;
            bp[t][jx] = (unsigned char)bi;
        }
        xa = xnext;
        STEP_BARRIER();
    };

    // Unrolled-by-2 main loop: compile-time LDS buffer pointers.
    int t = 1;
    for (; t + 1 < L; t += 2) {
        vstep(stateBuf[0], stateBuf[1], t);
        vstep(stateBuf[1], stateBuf[0], t + 1);
    }
    if (t < L) vstep(stateBuf[0], stateBuf[1], t);

    __syncthreads();   // full drain before epilogue
    const int pf = (L - 1) & 1;   // buffer holding the final state

    // Final argmax over state (first-occurrence: min index on ties).
    if (tid < NN) { redV[tid] = stateBuf[pf][SW(tid)]; redI[tid] = tid; }
    __syncthreads();
    #pragma unroll
    for (int off = 64; off >= 1; off >>= 1) {
        if (tid < off) {
            float va = redV[tid], vb = redV[tid + off];
            int   ia = redI[tid], ib = redI[tid + off];
            if (vb > va || (vb == va && ib < ia)) { redV[tid] = vb; redI[tid] = ib; }
        }
        __syncthreads();
    }

    // ---- Parallel backtrack via chunked function composition ----
    const int M = L - 1;
    const int G = (M + BD - 1) / BD;   // 0..8

    {   // pass 1: 4 interleaved chases per thread (independent LDS chains)
        int s  = tid & 127;
        int gb = (tid >> 7) << 2;      // 0 or 4
        int g0 = gb, g1 = gb + 1, g2 = gb + 2, g3 = gb + 3;
        int th0 = M - g0 * BD, th1 = M - g1 * BD;
        int th2 = M - g2 * BD, th3 = M - g3 * BD;
        int d0 = (g0 < G) ? ((th0 < BD) ? th0 : BD) : 0;
        int d1 = (g1 < G) ? ((th1 < BD) ? th1 : BD) : 0;
        int d2 = (g2 < G) ? ((th2 < BD) ? th2 : BD) : 0;
        int d3 = (g3 < G) ? ((th3 < BD) ? th3 : BD) : 0;
        int cu0 = s, cu1 = s, cu2 = s, cu3 = s;
        int maxd = d0;   // d0 >= d1 >= d2 >= d3 within a gb group
        for (int d = 0; d < maxd; ++d) {
            if (d < d0) { cu0 = bp[th0 - d][cu0]; hist[g0][d][s] = (unsigned char)cu0; }
            if (d < d1) { cu1 = bp[th1 - d][cu1]; hist[g1][d][s] = (unsigned char)cu1; }
            if (d < d2) { cu2 = bp[th2 - d][cu2]; hist[g2][d][s] = (unsigned char)cu2; }
            if (d < d3) { cu3 = bp[th3 - d][cu3]; hist[g3][d][s] = (unsigned char)cu3; }
        }
    }
    __syncthreads();

    if (tid == 0) {   // entry-tag scan across chunks (G <= 8 serial lookups)
        int e = redI[0];
        tagBuf[L - 1] = e;
        for (int g = 0; g < G; ++g) {
            entryTag[g] = e;
            if (g + 1 < G) e = hist[g][BD - 1][e];   // chunks < G-1 are full
        }
    }
    __syncthreads();

    {   // pass 2: copy winning histories into tagBuf (2 entries/thread)
        #pragma unroll
        for (int k = tid; k < MAXG * BD; k += NTHR) {
            int g = k >> 6, d = k & 63;
            if (g < G) {
                int th  = M - g * BD;
                int dep = (th < BD) ? th : BD;
                if (d < dep) {
                    int e = entryTag[g];
                    tagBuf[th - 1 - d] = hist[g][d][e];
                }
            }
        }
    }
    __syncthreads();

    // Coalesced output: tags for k < L, zeros for the masked tail.
    int* orow = out + (size_t)b * TT;
    #pragma unroll
    for (int k = tid; k < TT; k += NTHR) {
        orow[k] = (k < L) ? tagBuf[k] : 0;
    }
}

extern "C" void kernel_launch(void* const* d_in, const int* in_sizes, int n_in,
                              void* d_out, int out_size, void* d_ws, size_t ws_size,
                              hipStream_t stream) {
    const float* logits = (const float*)d_in[0];
    const float* trans  = (const float*)d_in[1];
    const int*   seqlen = (const int*)d_in[2];
    int*         out    = (int*)d_out;
    const int B = in_sizes[2];  // 256
    crf_viterbi_kernel<<<B, NTHR, 0, stream>>>(logits, trans, seqlen, out);
}

// Round 9
// 422.147 us; speedup vs baseline: 1.6900x; 1.6900x over previous
//
#include <hip/hip_runtime.h>

#define TT 512   // max sequence length T
#define NN 128   // number of tags N
#define NTHR 512 // 8 waves
#define SROW 160 // swizzled state row: 8 chunks x 20 floats (16 used + 4 pad)
#define SW(i) (20 * ((i) >> 4) + ((i) & 15))
#define BD  64   // (fallback kernel) backtrack chunk depth
#define MAXG 8   // (fallback kernel)

// Barrier WITHOUT vmcnt drain: LDS writes drained, global loads/stores stay
// in flight across the barrier.
#define STEP_BARRIER() asm volatile("s_waitcnt lgkmcnt(0)\n\ts_barrier" ::: "memory")

// DPP cross-lane (pure VALU, no LDS pipe)
template <int CTRL>
__device__ __forceinline__ int dpp_i(int x) {
    return __builtin_amdgcn_update_dpp(x, x, CTRL, 0xf, 0xf, true);
}
template <int CTRL>
__device__ __forceinline__ float dpp_f(float x) {
    union { float f; int i; } u; u.f = x;
    u.i = dpp_i<CTRL>(u.i);
    return u.f;
}
#define DPP_XOR1  0xB1   // quad_perm [1,0,3,2] : lane ^= 1
#define DPP_XOR2  0x4E   // quad_perm [2,3,0,1] : lane ^= 2
#define DPP_MIR7  0x141  // row_half_mirror (lane^=7): == ^4 after 1,2
#define DPP_MIR15 0x140  // row_mirror (lane^=15): == ^8 after 1,2,4

__device__ __forceinline__ float swz16_f(float x) {
    union { float f; int i; } u; u.f = x;
    u.i = __builtin_amdgcn_ds_swizzle(u.i, 0x401F);  // xor 16 (within 32)
    return u.f;
}
__device__ __forceinline__ int swz16_i(int x) {
    return __builtin_amdgcn_ds_swizzle(x, 0x401F);
}

// ---------------- FAST kernel: max-only forward + recompute backtrack -------
// One block per batch element. thread -> (j, c): j = tid>>3 serves tags j and
// j+64; c = tid&7 owns i-range [16c,16c+16). Forward: 2 VALU/eval (add +
// max3-fused tree), value-only DPP merge, state row -> LDS (stride-20
// swizzle) + global ws (for backtrack). Backtrack: wave 0 recomputes the one
// needed argmax per step from ws rows (4-deep prefetch) + LDS T^T; exact
// first-occurrence semantics (scores recomputed bitwise-identically).
__global__ __launch_bounds__(NTHR, 1)
void crf_viterbi_fast(const float* __restrict__ logits,
                      const float* __restrict__ trans,
                      const int* __restrict__ seqlen,
                      int* __restrict__ out,
                      float* __restrict__ ws) {
    __shared__ float stateBuf[2][SROW];
    __shared__ float tt[NN * NN];   // tt[j*128+i] = trans[i*128+j]  (64 KiB)
    __shared__ float redV[NN];
    __shared__ int   redI[NN];
    __shared__ int   tagBuf[TT];

    const int tid = threadIdx.x;
    const int j   = tid >> 3;   // 0..63 (serves j and j+64)
    const int c   = tid & 7;    // i-chunk
    const int i0  = c << 4;
    const int b   = blockIdx.x;
    const int L   = seqlen[b];  // in [1, TT]
    const int jx  = j + ((c & 1) << 6);

    // Transition chunks in registers
    float tr0[16], tr1[16];
    #pragma unroll
    for (int k = 0; k < 16; ++k) {
        tr0[k] = trans[(i0 + k) * NN + j];
        tr1[k] = trans[(i0 + k) * NN + j + 64];
    }

    // Transposed copy for backtrack (coalesced reads; one-time LDS write
    // conflicts are ~2k cyc, acceptable).
    #pragma unroll
    for (int k = 0; k < (NN * NN) / NTHR; ++k) {
        int idx = k * NTHR + tid;
        tt[(idx & 127) * NN + (idx >> 7)] = trans[idx];
    }

    const float* lrow = logits + (size_t)b * TT * NN;
    float* wsb = ws + (size_t)b * TT * NN;

    if (c < 2) {   // t = 0 init: LDS + ws row 0
        float v = lrow[jx];
        stateBuf[0][SW(jx)] = v;
        wsb[jx] = v;
    }
    __syncthreads();

    float xa = lrow[NN + jx];

    #define TAGMAX(TR, OUT)                                                    \
    {                                                                          \
        float c0=a0.x+TR[0], c1=a0.y+TR[1], c2=a0.z+TR[2],  c3=a0.w+TR[3];     \
        float c4=a1.x+TR[4], c5=a1.y+TR[5], c6=a1.z+TR[6],  c7=a1.w+TR[7];     \
        float c8=a2.x+TR[8], c9=a2.y+TR[9], c10=a2.z+TR[10],c11=a2.w+TR[11];   \
        float c12=a3.x+TR[12],c13=a3.y+TR[13],c14=a3.z+TR[14],c15=a3.w+TR[15]; \
        float t0=fmaxf(fmaxf(c0,c1),c2),  t1=fmaxf(fmaxf(c3,c4),c5);           \
        float t2=fmaxf(fmaxf(c6,c7),c8),  t3=fmaxf(fmaxf(c9,c10),c11);         \
        float t4=fmaxf(fmaxf(c12,c13),c14);                                    \
        OUT = fmaxf(fmaxf(fmaxf(t0,t1),t2), fmaxf(fmaxf(t3,t4),c15));          \
    }

    auto vstep = [&](const float* st, float* dst, int t) {
        int tn = (t + 1 < L) ? (t + 1) : (L - 1);
        float xnext = lrow[tn * NN + jx];

        const float* sp = st + 20 * c;
        float4 a0 = *(const float4*)(sp);
        float4 a1 = *(const float4*)(sp + 4);
        float4 a2 = *(const float4*)(sp + 8);
        float4 a3 = *(const float4*)(sp + 12);

        float bv0, bv1;
        TAGMAX(tr0, bv0)
        TAGMAX(tr1, bv1)

        // value-only octet merge (max is order-invariant -> exact)
        bv0 = fmaxf(bv0, dpp_f<DPP_XOR1>(bv0)); bv1 = fmaxf(bv1, dpp_f<DPP_XOR1>(bv1));
        bv0 = fmaxf(bv0, dpp_f<DPP_XOR2>(bv0)); bv1 = fmaxf(bv1, dpp_f<DPP_XOR2>(bv1));
        bv0 = fmaxf(bv0, dpp_f<DPP_MIR7>(bv0)); bv1 = fmaxf(bv1, dpp_f<DPP_MIR7>(bv1));

        if (c < 2) {
            float nv = (c ? bv1 : bv0) + xa;
            dst[SW(jx)] = nv;          // next step's input
            wsb[t * NN + jx] = nv;     // for backtrack (fire-and-forget)
        }
        xa = xnext;
        STEP_BARRIER();   // lgkm-only: global stores/loads stay in flight
    };
    #undef TAGMAX

    int t = 1;
    for (; t + 1 < L; t += 2) {
        vstep(stateBuf[0], stateBuf[1], t);
        vstep(stateBuf[1], stateBuf[0], t + 1);
    }
    if (t < L) vstep(stateBuf[0], stateBuf[1], t);

    __syncthreads();   // full drain: ws stores complete & visible
    const int pf = (L - 1) & 1;

    // Final argmax over state (first-occurrence: min index on ties).
    if (tid < NN) { redV[tid] = stateBuf[pf][SW(tid)]; redI[tid] = tid; }
    __syncthreads();
    #pragma unroll
    for (int off = 64; off >= 1; off >>= 1) {
        if (tid < off) {
            float va = redV[tid], vb = redV[tid + off];
            int   ia = redI[tid], ib = redI[tid + off];
            if (vb > va || (vb == va && ib < ia)) { redV[tid] = vb; redI[tid] = ib; }
        }
        __syncthreads();
    }

    // ---- Backtrack: wave 0 recomputes the needed argmax per step ----
    if (tid < 64) {
        const int lane = tid;
        const bool lw1 = (lane & 1), lw2 = (lane & 2), lw4 = (lane & 4),
                   lw8 = (lane & 8), lw16 = (lane & 16);
        int jcur = redI[0];
        if (lane == 0) tagBuf[L - 1] = jcur;

        auto loadrow = [&](int r) -> float2 {
            r = (r < 0) ? 0 : r;
            return *(const float2*)(wsb + r * NN + 2 * lane);
        };
        // step t: bp = argmax_i(S[t-1][i] + T[i][jcur]), exact first-occurrence
        auto chase = [&](float2 s2, int tc, int jc) -> int {
            float2 tp = *(const float2*)(tt + jc * NN + 2 * lane);
            float sA = s2.x + tp.x, sB = s2.y + tp.y;
            bool gB = sB > sA;                 // i=2*lane first-occurrence
            float v = gB ? sB : sA;
            int idx = 2 * lane + (gB ? 1 : 0);
            #define BSTAGE(PV, PI, LOW)                                        \
            {                                                                  \
                float pv = (PV); int pi = (PI);                                \
                bool tk = (pv > v) || (pv == v && (LOW));                      \
                v = tk ? pv : v; idx = tk ? pi : idx;                          \
            }
            BSTAGE(dpp_f<DPP_XOR1>(v),  dpp_i<DPP_XOR1>(idx),  lw1)
            BSTAGE(dpp_f<DPP_XOR2>(v),  dpp_i<DPP_XOR2>(idx),  lw2)
            BSTAGE(dpp_f<DPP_MIR7>(v),  dpp_i<DPP_MIR7>(idx),  lw4)
            BSTAGE(dpp_f<DPP_MIR15>(v), dpp_i<DPP_MIR15>(idx), lw8)
            BSTAGE(swz16_f(v),          swz16_i(idx),          lw16)
            #undef BSTAGE
            // cross-half combine via readlane (halves are uniform now)
            union { float f; int i; } uv; uv.f = v;
            int h0 = __builtin_amdgcn_readlane(uv.i, 0);
            int h1 = __builtin_amdgcn_readlane(uv.i, 32);
            int q0 = __builtin_amdgcn_readlane(idx, 0);
            int q1 = __builtin_amdgcn_readlane(idx, 32);
            union { int i; float f; } u0, u1; u0.i = h0; u1.i = h1;
            int jn = (u1.f > u0.f) ? q1 : q0;   // tie -> lower half (lower i)
            if (lane == 0) tagBuf[tc - 1] = jn;
            return jn;
        };

        // 4-deep row prefetch, statically unrolled ring (no dynamic reg index)
        float2 r0 = loadrow(L - 2), r1 = loadrow(L - 3);
        float2 r2 = loadrow(L - 4), r3 = loadrow(L - 5);
        int tb = L - 1;
        while (tb >= 4) {
            jcur = chase(r0, tb,     jcur); r0 = loadrow(tb - 5);
            jcur = chase(r1, tb - 1, jcur); r1 = loadrow(tb - 6);
            jcur = chase(r2, tb - 2, jcur); r2 = loadrow(tb - 7);
            jcur = chase(r3, tb - 3, jcur); r3 = loadrow(tb - 8);
            tb -= 4;
        }
        if (tb >= 1) jcur = chase(r0, tb, jcur);
        if (tb >= 2) jcur = chase(r1, tb - 1, jcur);
        if (tb >= 3) jcur = chase(r2, tb - 2, jcur);
    }
    __syncthreads();

    // Coalesced output: tags for k < L, zeros for the masked tail.
    out[(size_t)b * TT + tid] = (tid < L) ? tagBuf[tid] : 0;
}

// ---------------- FALLBACK kernel: R5 (proven 425 us), used if ws too small -
__global__ __launch_bounds__(NTHR, 1)
void crf_viterbi_fallback(const float* __restrict__ logits,
                          const float* __restrict__ trans,
                          const int* __restrict__ seqlen,
                          int* __restrict__ out) {
    __shared__ float stateBuf[2][SROW];
    __shared__ float redV[NN];
    __shared__ int   redI[NN];
    __shared__ int   tagBuf[TT];
    __shared__ int   entryTag[MAXG];
    __shared__ unsigned char bp[TT][NN];
    __shared__ unsigned char hist[MAXG][BD][NN];

    const int tid = threadIdx.x;
    const int j   = tid >> 3;
    const int c   = tid & 7;
    const int i0  = c << 4;
    const int b   = blockIdx.x;
    const int L   = seqlen[b];

    float tr0[16], tr1[16];
    #pragma unroll
    for (int k = 0; k < 16; ++k) {
        tr0[k] = trans[(i0 + k) * NN + j];
        tr1[k] = trans[(i0 + k) * NN + j + 64];
    }

    const float* lrow = logits + (size_t)b * TT * NN;
    if (c < 2) {
        int jj = j + (c << 6);
        stateBuf[0][SW(jj)] = lrow[jj];
    }
    __syncthreads();

    float xa0 = lrow[NN + j], xa1 = lrow[NN + j + 64];
    int p = 0;
    for (int t = 1; t < L; ++t) {
        int tn = (t + 1 < L) ? (t + 1) : (L - 1);
        const float* lp = lrow + tn * NN;
        float xb0 = lp[j];
        float xb1 = lp[j + 64];

        const float* st = stateBuf[p] + 20 * c;
        float4 a0 = *(const float4*)(st);
        float4 a1 = *(const float4*)(st + 4);
        float4 a2 = *(const float4*)(st + 8);
        float4 a3 = *(const float4*)(st + 12);

        float best0 = -__builtin_inff(), best1 = -__builtin_inff();
        int arg0 = 0, arg1 = 0;
        #define ELEM(S, K)                                                  \
        {                                                                   \
            float sc = (S) + tr0[K];                                        \
            bool g = sc > best0; best0 = g ? sc : best0; arg0 = g ? (K) : arg0; \
            float sd = (S) + tr1[K];                                        \
            bool h = sd > best1; best1 = h ? sd : best1; arg1 = h ? (K) : arg1; \
        }
        ELEM(a0.x, 0)  ELEM(a0.y, 1)  ELEM(a0.z, 2)  ELEM(a0.w, 3)
        ELEM(a1.x, 4)  ELEM(a1.y, 5)  ELEM(a1.z, 6)  ELEM(a1.w, 7)
        ELEM(a2.x, 8)  ELEM(a2.y, 9)  ELEM(a2.z, 10) ELEM(a2.w, 11)
        ELEM(a3.x, 12) ELEM(a3.y, 13) ELEM(a3.z, 14) ELEM(a3.w, 15)
        #undef ELEM

        float bv0 = best0, bv1 = best1;
        int   bi0 = i0 + arg0, bi1 = i0 + arg1;
        #define MERGE_STAGE(CTRL, LOWER)                                   \
        {                                                                  \
            float p0 = dpp_f<CTRL>(bv0); int q0 = dpp_i<CTRL>(bi0);        \
            float p1 = dpp_f<CTRL>(bv1); int q1 = dpp_i<CTRL>(bi1);        \
            bool lower = (LOWER);                                          \
            bool t0 = (p0 > bv0) || (p0 == bv0 && lower);                  \
            bool t1 = (p1 > bv1) || (p1 == bv1 && lower);                  \
            bv0 = t0 ? p0 : bv0; bi0 = t0 ? q0 : bi0;                      \
            bv1 = t1 ? p1 : bv1; bi1 = t1 ? q1 : bi1;                      \
        }
        MERGE_STAGE(DPP_XOR1, (c & 1) != 0)
        MERGE_STAGE(DPP_XOR2, (c & 2) != 0)
        MERGE_STAGE(DPP_MIR7, (c & 4) != 0)
        #undef MERGE_STAGE

        if (c < 2) {
            int   jj = j + (c << 6);
            float bv = c ? bv1 : bv0;
            int   bi = c ? bi1 : bi0;
            float xx = c ? xa1 : xa0;
            stateBuf[p ^ 1][SW(jj)] = bv + xx;
            bp[t][jj] = (unsigned char)bi;
        }
        xa0 = xb0; xa1 = xb1;
        __syncthreads();
        p ^= 1;
    }

    if (tid < NN) { redV[tid] = stateBuf[p][SW(tid)]; redI[tid] = tid; }
    __syncthreads();
    #pragma unroll
    for (int off = 64; off >= 1; off >>= 1) {
        if (tid < off) {
            float va = redV[tid], vb = redV[tid + off];
            int   ia = redI[tid], ib = redI[tid + off];
            if (vb > va || (vb == va && ib < ia)) { redV[tid] = vb; redI[tid] = ib; }
        }
        __syncthreads();
    }

    const int M = L - 1;
    const int G = (M + BD - 1) / BD;
    {
        int s  = tid & 127;
        int gA = tid >> 7;
        int gB = gA + 4;
        int thA = M - gA * BD, thB = M - gB * BD;
        int dA  = (gA < G) ? ((thA < BD) ? thA : BD) : 0;
        int dB  = (gB < G) ? ((thB < BD) ? thB : BD) : 0;
        int curA = s, curB = s;
        int maxd = (dA > dB) ? dA : dB;
        for (int d = 0; d < maxd; ++d) {
            if (d < dA) { curA = bp[thA - d][curA]; hist[gA][d][s] = (unsigned char)curA; }
            if (d < dB) { curB = bp[thB - d][curB]; hist[gB][d][s] = (unsigned char)curB; }
        }
    }
    __syncthreads();
    if (tid == 0) {
        int e = redI[0];
        tagBuf[L - 1] = e;
        for (int g = 0; g < G; ++g) {
            entryTag[g] = e;
            if (g + 1 < G) e = hist[g][BD - 1][e];
        }
    }
    __syncthreads();
    {
        int g = tid >> 6, d = tid & 63;
        if (g < MAXG && g < G) {
            int th  = M - g * BD;
            int dep = (th < BD) ? th : BD;
            if (d < dep) {
                int e = entryTag[g];
                tagBuf[th - 1 - d] = hist[g][d][e];
            }
        }
    }
    __syncthreads();
    out[(size_t)b * TT + tid] = (tid < L) ? tagBuf[tid] : 0;
}

extern "C" void kernel_launch(void* const* d_in, const int* in_sizes, int n_in,
                              void* d_out, int out_size, void* d_ws, size_t ws_size,
                              hipStream_t stream) {
    const float* logits = (const float*)d_in[0];
    const float* trans  = (const float*)d_in[1];
    const int*   seqlen = (const int*)d_in[2];
    int*         out    = (int*)d_out;
    const int B = in_sizes[2];  // 256
    const size_t need = (size_t)B * TT * NN * sizeof(float);  // 64 MiB
    if (ws_size >= need) {
        crf_viterbi_fast<<<B, NTHR, 0, stream>>>(logits, trans, seqlen, out,
                                                 (float*)d_ws);
    } else {
        crf_viterbi_fallback<<<B, NTHR, 0, stream>>>(logits, trans, seqlen, out);
    }
}

// Round 10
// 313.942 us; speedup vs baseline: 2.2724x; 1.3447x over previous
//
#include <hip/hip_runtime.h>

#define TT 512   // max sequence length T
#define NN 128   // number of tags N
#define NTHR 512 // 8 waves
#define SROW 160 // swizzled state row: 8 chunks x 20 floats (16 used + 4 pad)
#define SW(i) (20 * ((i) >> 4) + ((i) & 15))
#define TTS 130  // tt (T^T) row stride in floats: bank step 2, float2-aligned
#define BD  64   // (fallback kernel) backtrack chunk depth
#define MAXG 8   // (fallback kernel)

// Barrier WITHOUT vmcnt drain: LDS writes drained, global loads/stores stay
// in flight across the barrier.
#define STEP_BARRIER() asm volatile("s_waitcnt lgkmcnt(0)\n\ts_barrier" ::: "memory")

// DPP cross-lane (pure VALU, no LDS pipe)
template <int CTRL>
__device__ __forceinline__ int dpp_i(int x) {
    return __builtin_amdgcn_update_dpp(x, x, CTRL, 0xf, 0xf, true);
}
template <int CTRL>
__device__ __forceinline__ float dpp_f(float x) {
    union { float f; int i; } u; u.f = x;
    u.i = dpp_i<CTRL>(u.i);
    return u.f;
}
#define DPP_XOR1 0xB1   // quad_perm [1,0,3,2] : lane ^= 1
#define DPP_XOR2 0x4E   // quad_perm [2,3,0,1] : lane ^= 2
#define DPP_MIR7 0x141  // row_half_mirror (lane^=7): == ^4 after 1,2

// ---------------- FAST kernel: max-only forward + equality-ballot backtrack -
// Forward (identical structure to R9): thread (j,c), j=tid>>3 serves tags j,
// j+64; c=tid&7 owns i-range [16c,16c+16). 2 VALU/eval max-only, value-only
// DPP merge, state -> LDS; pre-logit max M[t][j] -> ws (plus row 0 = zeros).
// Backtrack: wave 0; candidates recomputed bitwise-identically, backpointer =
// first i with candidate == M[t][jc] via v_cmp_eq + ballot + ffs (exact
// first-occurrence). Target for step t-1 extracted from the row just used.
__global__ __launch_bounds__(NTHR, 1)
void crf_viterbi_fast(const float* __restrict__ logits,
                      const float* __restrict__ trans,
                      const int* __restrict__ seqlen,
                      int* __restrict__ out,
                      float* __restrict__ ws) {
    __shared__ float stateBuf[2][SROW];
    __shared__ float tt[NN * TTS];  // tt[j*TTS+i] = trans[i*NN+j]
    __shared__ float redV[NN];
    __shared__ int   redI[NN];
    __shared__ int   tagBuf[TT];

    const int tid = threadIdx.x;
    const int j   = tid >> 3;   // 0..63 (serves j and j+64)
    const int c   = tid & 7;    // i-chunk
    const int i0  = c << 4;
    const int b   = blockIdx.x;
    const int L   = seqlen[b];  // in [1, TT]
    const int jx  = j + ((c & 1) << 6);

    // Transition chunks in registers
    float tr0[16], tr1[16];
    #pragma unroll
    for (int k = 0; k < 16; ++k) {
        tr0[k] = trans[(i0 + k) * NN + j];
        tr1[k] = trans[(i0 + k) * NN + j + 64];
    }

    // Transposed copy for backtrack. Stride TTS=130: write bank step 2
    // (4-way conflict instead of 32-way at stride 128), reads float2-aligned.
    #pragma unroll
    for (int k = 0; k < (NN * NN) / NTHR; ++k) {
        int idx = k * NTHR + tid;
        tt[(idx & 127) * TTS + (idx >> 7)] = trans[idx];
    }

    const float* lrow = logits + (size_t)b * TT * NN;
    float* wsb = ws + (size_t)b * TT * NN;

    if (c < 2) {   // t = 0 init: LDS state = x[0]; ws row 0 = 0 (M[0] := 0)
        stateBuf[0][SW(jx)] = lrow[jx];
        wsb[jx] = 0.0f;
    }
    __syncthreads();

    float xa = lrow[NN + jx];

    #define TAGMAX(TR, OUT)                                                    \
    {                                                                          \
        float c0=a0.x+TR[0], c1=a0.y+TR[1], c2=a0.z+TR[2],  c3=a0.w+TR[3];     \
        float c4=a1.x+TR[4], c5=a1.y+TR[5], c6=a1.z+TR[6],  c7=a1.w+TR[7];     \
        float c8=a2.x+TR[8], c9=a2.y+TR[9], c10=a2.z+TR[10],c11=a2.w+TR[11];   \
        float c12=a3.x+TR[12],c13=a3.y+TR[13],c14=a3.z+TR[14],c15=a3.w+TR[15]; \
        float t0=fmaxf(fmaxf(c0,c1),c2),  t1=fmaxf(fmaxf(c3,c4),c5);           \
        float t2=fmaxf(fmaxf(c6,c7),c8),  t3=fmaxf(fmaxf(c9,c10),c11);         \
        float t4=fmaxf(fmaxf(c12,c13),c14);                                    \
        OUT = fmaxf(fmaxf(fmaxf(t0,t1),t2), fmaxf(fmaxf(t3,t4),c15));          \
    }

    auto vstep = [&](const float* st, float* dst, int t) {
        int tn = (t + 1 < L) ? (t + 1) : (L - 1);
        float xnext = lrow[tn * NN + jx];

        const float* sp = st + 20 * c;
        float4 a0 = *(const float4*)(sp);
        float4 a1 = *(const float4*)(sp + 4);
        float4 a2 = *(const float4*)(sp + 8);
        float4 a3 = *(const float4*)(sp + 12);

        float bv0, bv1;
        TAGMAX(tr0, bv0)
        TAGMAX(tr1, bv1)

        // value-only octet merge (max is order-invariant -> exact)
        bv0 = fmaxf(bv0, dpp_f<DPP_XOR1>(bv0)); bv1 = fmaxf(bv1, dpp_f<DPP_XOR1>(bv1));
        bv0 = fmaxf(bv0, dpp_f<DPP_XOR2>(bv0)); bv1 = fmaxf(bv1, dpp_f<DPP_XOR2>(bv1));
        bv0 = fmaxf(bv0, dpp_f<DPP_MIR7>(bv0)); bv1 = fmaxf(bv1, dpp_f<DPP_MIR7>(bv1));

        if (c < 2) {
            float bv = c ? bv1 : bv0;
            dst[SW(jx)] = bv + xa;     // next step's state S[t]
            wsb[t * NN + jx] = bv;     // pre-logit max M[t] (for backtrack)
        }
        xa = xnext;
        STEP_BARRIER();   // lgkm-only: global stores/loads stay in flight
    };
    #undef TAGMAX

    int t = 1;
    for (; t + 1 < L; t += 2) {
        vstep(stateBuf[0], stateBuf[1], t);
        vstep(stateBuf[1], stateBuf[0], t + 1);
    }
    if (t < L) vstep(stateBuf[0], stateBuf[1], t);

    __syncthreads();   // full drain: ws stores complete & visible
    const int pf = (L - 1) & 1;

    // Final argmax over state (first-occurrence: min index on ties).
    if (tid < NN) { redV[tid] = stateBuf[pf][SW(tid)]; redI[tid] = tid; }
    __syncthreads();
    #pragma unroll
    for (int off = 64; off >= 1; off >>= 1) {
        if (tid < off) {
            float va = redV[tid], vb = redV[tid + off];
            int   ia = redI[tid], ib = redI[tid + off];
            if (vb > va || (vb == va && ib < ia)) { redV[tid] = vb; redI[tid] = ib; }
        }
        __syncthreads();
    }

    // ---- Backtrack: wave 0, equality-ballot chase ----
    if (tid < 64) {
        const int lane = tid;
        int jc = redI[0];
        if (lane == 0) tagBuf[L - 1] = jc;

        auto wrow = [&](int r) -> float2 {   // M row (clamped; clamped rows unused)
            r = (r < 0) ? 0 : r;
            return *(const float2*)(wsb + r * NN + 2 * lane);
        };
        auto xrow = [&](int r) -> float2 {   // logits row
            r = (r < 0) ? 0 : r;
            return *(const float2*)(lrow + r * NN + 2 * lane);
        };
        auto extract2 = [&](float2 v, int idx) -> float {  // v[idx], idx uniform
            int sel = idx >> 1;
            int wx = __builtin_amdgcn_readlane(__float_as_int(v.x), sel);
            int wy = __builtin_amdgcn_readlane(__float_as_int(v.y), sel);
            return __int_as_float((idx & 1) ? wy : wx);
        };

        float2 rT = wrow(L - 1);
        float target = extract2(rT, jc);     // M[L-1][jc]

        // chase step t: uses m = M[t-1] row, xr = x[t-1] row.
        // bp = first i with (m[i]+xr[i])+T[i][jc] == target (bitwise-exact
        // recompute of forward candidates -> exact first-occurrence argmax).
        auto chase = [&](float2 m, float2 xr, int tc) {
            float2 tp = *(const float2*)(tt + jc * TTS + 2 * lane);
            float cA = (m.x + xr.x) + tp.x;
            float cB = (m.y + xr.y) + tp.y;
            unsigned long long mA = __ballot(cA == target);
            unsigned long long mB = __ballot(cB == target);
            int iA = mA ? (2 * (__ffsll(mA) - 1))     : (1 << 30);
            int iB = mB ? (2 * (__ffsll(mB) - 1) + 1) : (1 << 30);
            int bp = (iA < iB) ? iA : iB;
            if (lane == 0) tagBuf[tc - 1] = bp;
            target = extract2(m, bp);        // M[t-1][bp] for the next step
            jc = bp;
        };

        // 4-deep prefetch ring, statically unrolled
        float2 m0 = wrow(L - 2), x0 = xrow(L - 2);
        float2 m1 = wrow(L - 3), x1 = xrow(L - 3);
        float2 m2 = wrow(L - 4), x2 = xrow(L - 4);
        float2 m3 = wrow(L - 5), x3 = xrow(L - 5);
        int tb = L - 1;
        while (tb >= 4) {
            chase(m0, x0, tb);     m0 = wrow(tb - 5); x0 = xrow(tb - 5);
            chase(m1, x1, tb - 1); m1 = wrow(tb - 6); x1 = xrow(tb - 6);
            chase(m2, x2, tb - 2); m2 = wrow(tb - 7); x2 = xrow(tb - 7);
            chase(m3, x3, tb - 3); m3 = wrow(tb - 8); x3 = xrow(tb - 8);
            tb -= 4;
        }
        if (tb >= 1) chase(m0, x0, tb);
        if (tb >= 2) chase(m1, x1, tb - 1);
        if (tb >= 3) chase(m2, x2, tb - 2);
    }
    __syncthreads();

    // Coalesced output: tags for k < L, zeros for the masked tail.
    out[(size_t)b * TT + tid] = (tid < L) ? tagBuf[tid] : 0;
}

// ---------------- FALLBACK kernel: R5 (proven), used if ws too small --------
__global__ __launch_bounds__(NTHR, 1)
void crf_viterbi_fallback(const float* __restrict__ logits,
                          const float* __restrict__ trans,
                          const int* __restrict__ seqlen,
                          int* __restrict__ out) {
    __shared__ float stateBuf[2][SROW];
    __shared__ float redV[NN];
    __shared__ int   redI[NN];
    __shared__ int   tagBuf[TT];
    __shared__ int   entryTag[MAXG];
    __shared__ unsigned char bp[TT][NN];
    __shared__ unsigned char hist[MAXG][BD][NN];

    const int tid = threadIdx.x;
    const int j   = tid >> 3;
    const int c   = tid & 7;
    const int i0  = c << 4;
    const int b   = blockIdx.x;
    const int L   = seqlen[b];

    float tr0[16], tr1[16];
    #pragma unroll
    for (int k = 0; k < 16; ++k) {
        tr0[k] = trans[(i0 + k) * NN + j];
        tr1[k] = trans[(i0 + k) * NN + j + 64];
    }

    const float* lrow = logits + (size_t)b * TT * NN;
    if (c < 2) {
        int jj = j + (c << 6);
        stateBuf[0][SW(jj)] = lrow[jj];
    }
    __syncthreads();

    float xa0 = lrow[NN + j], xa1 = lrow[NN + j + 64];
    int p = 0;
    for (int t = 1; t < L; ++t) {
        int tn = (t + 1 < L) ? (t + 1) : (L - 1);
        const float* lp = lrow + tn * NN;
        float xb0 = lp[j];
        float xb1 = lp[j + 64];

        const float* st = stateBuf[p] + 20 * c;
        float4 a0 = *(const float4*)(st);
        float4 a1 = *(const float4*)(st + 4);
        float4 a2 = *(const float4*)(st + 8);
        float4 a3 = *(const float4*)(st + 12);

        float best0 = -__builtin_inff(), best1 = -__builtin_inff();
        int arg0 = 0, arg1 = 0;
        #define ELEM(S, K)                                                  \
        {                                                                   \
            float sc = (S) + tr0[K];                                        \
            bool g = sc > best0; best0 = g ? sc : best0; arg0 = g ? (K) : arg0; \
            float sd = (S) + tr1[K];                                        \
            bool h = sd > best1; best1 = h ? sd : best1; arg1 = h ? (K) : arg1; \
        }
        ELEM(a0.x, 0)  ELEM(a0.y, 1)  ELEM(a0.z, 2)  ELEM(a0.w, 3)
        ELEM(a1.x, 4)  ELEM(a1.y, 5)  ELEM(a1.z, 6)  ELEM(a1.w, 7)
        ELEM(a2.x, 8)  ELEM(a2.y, 9)  ELEM(a2.z, 10) ELEM(a2.w, 11)
        ELEM(a3.x, 12) ELEM(a3.y, 13) ELEM(a3.z, 14) ELEM(a3.w, 15)
        #undef ELEM

        float bv0 = best0, bv1 = best1;
        int   bi0 = i0 + arg0, bi1 = i0 + arg1;
        #define MERGE_STAGE(CTRL, LOWER)                                   \
        {                                                                  \
            float p0 = dpp_f<CTRL>(bv0); int q0 = dpp_i<CTRL>(bi0);        \
            float p1 = dpp_f<CTRL>(bv1); int q1 = dpp_i<CTRL>(bi1);        \
            bool lower = (LOWER);                                          \
            bool t0 = (p0 > bv0) || (p0 == bv0 && lower);                  \
            bool t1 = (p1 > bv1) || (p1 == bv1 && lower);                  \
            bv0 = t0 ? p0 : bv0; bi0 = t0 ? q0 : bi0;                      \
            bv1 = t1 ? p1 : bv1; bi1 = t1 ? q1 : bi1;                      \
        }
        MERGE_STAGE(DPP_XOR1, (c & 1) != 0)
        MERGE_STAGE(DPP_XOR2, (c & 2) != 0)
        MERGE_STAGE(DPP_MIR7, (c & 4) != 0)
        #undef MERGE_STAGE

        if (c < 2) {
            int   jj = j + (c << 6);
            float bv = c ? bv1 : bv0;
            int   bi = c ? bi1 : bi0;
            float xx = c ? xa1 : xa0;
            stateBuf[p ^ 1][SW(jj)] = bv + xx;
            bp[t][jj] = (unsigned char)bi;
        }
        xa0 = xb0; xa1 = xb1;
        __syncthreads();
        p ^= 1;
    }

    if (tid < NN) { redV[tid] = stateBuf[p][SW(tid)]; redI[tid] = tid; }
    __syncthreads();
    #pragma unroll
    for (int off = 64; off >= 1; off >>= 1) {
        if (tid < off) {
            float va = redV[tid], vb = redV[tid + off];
            int   ia = redI[tid], ib = redI[tid + off];
            if (vb > va || (vb == va && ib < ia)) { redV[tid] = vb; redI[tid] = ib; }
        }
        __syncthreads();
    }

    const int M = L - 1;
    const int G = (M + BD - 1) / BD;
    {
        int s  = tid & 127;
        int gA = tid >> 7;
        int gB = gA + 4;
        int thA = M - gA * BD, thB = M - gB * BD;
        int dA  = (gA < G) ? ((thA < BD) ? thA : BD) : 0;
        int dB  = (gB < G) ? ((thB < BD) ? thB : BD) : 0;
        int curA = s, curB = s;
        int maxd = (dA > dB) ? dA : dB;
        for (int d = 0; d < maxd; ++d) {
            if (d < dA) { curA = bp[thA - d][curA]; hist[gA][d][s] = (unsigned char)curA; }
            if (d < dB) { curB = bp[thB - d][curB]; hist[gB][d][s] = (unsigned char)curB; }
        }
    }
    __syncthreads();
    if (tid == 0) {
        int e = redI[0];
        tagBuf[L - 1] = e;
        for (int g = 0; g < G; ++g) {
            entryTag[g] = e;
            if (g + 1 < G) e = hist[g][BD - 1][e];
        }
    }
    __syncthreads();
    {
        int g = tid >> 6, d = tid & 63;
        if (g < MAXG && g < G) {
            int th  = M - g * BD;
            int dep = (th < BD) ? th : BD;
            if (d < dep) {
                int e = entryTag[g];
                tagBuf[th - 1 - d] = hist[g][d][e];
            }
        }
    }
    __syncthreads();
    out[(size_t)b * TT + tid] = (tid < L) ? tagBuf[tid] : 0;
}

extern "C" void kernel_launch(void* const* d_in, const int* in_sizes, int n_in,
                              void* d_out, int out_size, void* d_ws, size_t ws_size,
                              hipStream_t stream) {
    const float* logits = (const float*)d_in[0];
    const float* trans  = (const float*)d_in[1];
    const int*   seqlen = (const int*)d_in[2];
    int*         out    = (int*)d_out;
    const int B = in_sizes[2];  // 256
    const size_t need = (size_t)B * TT * NN * sizeof(float);  // 64 MiB
    if (ws_size >= need) {
        crf_viterbi_fast<<<B, NTHR, 0, stream>>>(logits, trans, seqlen, out,
                                                 (float*)d_ws);
    } else {
        crf_viterbi_fallback<<<B, NTHR, 0, stream>>>(logits, trans, seqlen, out);
    }
}